// Round 4
// baseline (104.136 us; speedup 1.0000x reference)
//
#include <hip/hip_runtime.h>

// ConvDeepSet: B=8, N_IN=1024, N_OUT=4096, OUT_CHANNELS=64
//
// *** DIAGNOSTIC ROUND (retry — R3 hit GPUAcquisitionTimeout, never ran). ***
// Identical kernel to R2, launched 4x back-to-back. dur_us includes a ~70us
// harness reset floor (256MiB ws poison fill ~41us + restores + node gaps);
// the kernel's own dispatch never shows in the top-5 counter rows.
// kernel_time = (dur_4x - dur_1x_R2) / 3.
//
// Kernel logic (unchanged from R2):
// dens[b,m] = sum_n exp(k0*d(n,m)), conv[b,m] = sum_n y[n] exp(k1*d(n,m))
// out[b,m,o] = dens*W[o,0] + (conv/(dens+1e-8))*W[o,1] + b[o]
// Fast path (actual data: sigma[0]==sigma[1] -> r==1): ONE exp per pair,
// coords prescaled by s=sqrt(-k0) so arg = -(dx^2+dy^2).

#define OUTC 64
#define MB   128

__global__ __launch_bounds__(1024) void convdeepset_kernel(
    const float* __restrict__ x,     // [B,1024,2]
    const float* __restrict__ y,     // [B,1024]
    const float* __restrict__ t,     // [B,4096,2]
    const float* __restrict__ sigma, // [2]
    const float* __restrict__ W,     // [64,2]
    const float* __restrict__ bias,  // [64]
    float* __restrict__ out)         // [B,4096,64]
{
    __shared__ float4 pk[512];           // 8 KB: (x0a,x1a,x0b,x1b) prescaled
    __shared__ float2 yy[512];           // 4 KB: (ya,yb)
    __shared__ float  dens_part[16*MB];  // 8 KB
    __shared__ float  conv_part[16*MB];  // 8 KB
    __shared__ float  sums[2*MB];
    __shared__ float  dens_tot[MB];
    __shared__ float  ratio[MB];

    const int tid = threadIdx.x;
    const int b   = blockIdx.x >> 5;         // 32 m-tiles per batch
    const int m0  = (blockIdx.x & 31) * MB;

    const float log2e = 1.44269504088896340736f;
    const float k0 = -0.5f * __expf(-2.0f * sigma[0]) * log2e;
    const float k1 = -0.5f * __expf(-2.0f * sigma[1]) * log2e;
    const float s0 = sqrtf(-k0);
    const float r  = k1 / k0;            // arg1 = arg0 * r (uniform)

    if (tid < 512) {
        const float4* xg = (const float4*)(x + (size_t)b * 2048);
        float4 xv = xg[tid];
        xv.x *= s0; xv.y *= s0; xv.z *= s0; xv.w *= s0;
        pk[tid] = xv;
    } else {
        const float2* yg = (const float2*)(y + (size_t)b * 1024);
        yy[tid - 512] = yg[tid - 512];
    }

    const int wave = tid >> 6;
    const int lane = tid & 63;
    const float2* tg = (const float2*)(t + ((size_t)b * 4096 + m0) * 2);
    const float2 ta = tg[lane];
    const float2 tb = tg[64 + lane];
    const float t0x = ta.x * s0, t0y = ta.y * s0;
    const float t1x = tb.x * s0, t1y = tb.y * s0;

    __syncthreads();

    float d0 = 0.f, c0 = 0.f, d1 = 0.f, c1 = 0.f;
    const int ibeg = wave * 32;

    if (r == 1.0f) {
        #pragma unroll 4
        for (int i = ibeg; i < ibeg + 32; ++i) {
            const float4 p  = pk[i];
            const float2 yv = yy[i];
            {
                float dx = p.x - t0x, dy = p.y - t0y;
                float e = __builtin_amdgcn_exp2f(fmaf(dx, -dx, -(dy * dy)));
                d0 += e; c0 = fmaf(yv.x, e, c0);
            }
            {
                float dx = p.x - t1x, dy = p.y - t1y;
                float e = __builtin_amdgcn_exp2f(fmaf(dx, -dx, -(dy * dy)));
                d1 += e; c1 = fmaf(yv.x, e, c1);
            }
            {
                float dx = p.z - t0x, dy = p.w - t0y;
                float e = __builtin_amdgcn_exp2f(fmaf(dx, -dx, -(dy * dy)));
                d0 += e; c0 = fmaf(yv.y, e, c0);
            }
            {
                float dx = p.z - t1x, dy = p.w - t1y;
                float e = __builtin_amdgcn_exp2f(fmaf(dx, -dx, -(dy * dy)));
                d1 += e; c1 = fmaf(yv.y, e, c1);
            }
        }
    } else {
        #pragma unroll 2
        for (int i = ibeg; i < ibeg + 32; ++i) {
            const float4 p  = pk[i];
            const float2 yv = yy[i];
            {
                float dx = p.x - t0x, dy = p.y - t0y;
                float a  = fmaf(dx, -dx, -(dy * dy));
                d0 += __builtin_amdgcn_exp2f(a);
                c0 = fmaf(yv.x, __builtin_amdgcn_exp2f(a * r), c0);
            }
            {
                float dx = p.x - t1x, dy = p.y - t1y;
                float a  = fmaf(dx, -dx, -(dy * dy));
                d1 += __builtin_amdgcn_exp2f(a);
                c1 = fmaf(yv.x, __builtin_amdgcn_exp2f(a * r), c1);
            }
            {
                float dx = p.z - t0x, dy = p.w - t0y;
                float a  = fmaf(dx, -dx, -(dy * dy));
                d0 += __builtin_amdgcn_exp2f(a);
                c0 = fmaf(yv.y, __builtin_amdgcn_exp2f(a * r), c0);
            }
            {
                float dx = p.z - t1x, dy = p.w - t1y;
                float a  = fmaf(dx, -dx, -(dy * dy));
                d1 += __builtin_amdgcn_exp2f(a);
                c1 = fmaf(yv.y, __builtin_amdgcn_exp2f(a * r), c1);
            }
        }
    }

    dens_part[wave * MB + lane]      = d0;
    dens_part[wave * MB + 64 + lane] = d1;
    conv_part[wave * MB + lane]      = c0;
    conv_part[wave * MB + 64 + lane] = c1;
    __syncthreads();

    if (tid < 256) {
        const int m = tid & (MB - 1);
        const float* src = (tid < MB) ? dens_part : conv_part;
        float s = 0.f;
        #pragma unroll
        for (int w = 0; w < 16; ++w) s += src[w * MB + m];
        sums[tid] = s;
    }
    __syncthreads();
    if (tid < MB) {
        float dt = sums[tid];
        dens_tot[tid] = dt;
        ratio[tid]    = sums[MB + tid] / (dt + 1e-8f);
    }
    __syncthreads();

    const int o = tid & 63;
    const int g = tid >> 6;
    const float w0 = W[o * 2 + 0];
    const float w1 = W[o * 2 + 1];
    const float bo = bias[o];
    float* outb = out + ((size_t)b * 4096 + m0) * OUTC;
    #pragma unroll
    for (int i = 0; i < 8; ++i) {
        int mm = g * 8 + i;
        outb[mm * OUTC + o] = fmaf(dens_tot[mm], w0, fmaf(ratio[mm], w1, bo));
    }
}

extern "C" void kernel_launch(void* const* d_in, const int* in_sizes, int n_in,
                              void* d_out, int out_size, void* d_ws, size_t ws_size,
                              hipStream_t stream) {
    const float* x     = (const float*)d_in[0];
    const float* y     = (const float*)d_in[1];
    const float* t     = (const float*)d_in[2];
    const float* sigma = (const float*)d_in[3];
    const float* W     = (const float*)d_in[4];
    const float* bias  = (const float*)d_in[5];
    float* out = (float*)d_out;

    // DIAGNOSTIC: 4 identical launches (idempotent). kernel_time =
    // (dur_4x - dur_1x_R2) / 3. Revert to single launch next round.
    for (int rep = 0; rep < 4; ++rep) {
        convdeepset_kernel<<<dim3(256), dim3(1024), 0, stream>>>(
            x, y, t, sigma, W, bias, out);
    }
}

// Round 5
// 72.571 us; speedup vs baseline: 1.4350x; 1.4350x over previous
//
#include <hip/hip_runtime.h>

// ConvDeepSet: B=8, N_IN=1024, N_OUT=4096, OUT_CHANNELS=64
//
// dens[b,m] = sum_n exp(k0*d(n,m)), conv[b,m] = sum_n y[n] exp(k1*d(n,m))
// out[b,m,o] = dens*W[o,0] + (conv/(dens+1e-8))*W[o,1] + b[o]
// k = -0.5*exp(-2*sigma)*log2(e); exp via v_exp_f32 (exp2).
//
// Dot-product form: with s = sqrt(-k0), scaled exponent
//   arg = -(|s*x - s*t|^2) = (q_n + cm) + px*u + py*v   (arg <= 0 always)
// where per-n LDS record pk[n] = (2*s*x0, 2*s*x1, q_n=-|s*x|^2, y_n)  [float4]
// and per-m regs u = s*t0, v = s*t1, cm = -|s*t|^2.
// Inner pair = 5 VALU + 1 trans: add, fma, fma, exp2, add, fma.
// (cm must stay inside the exponent: q+dot alone reaches ~+5900 -> exp2 inf.)
//
// Fast path r = k1/k0 == 1 (actual data: sigma[0]==sigma[1]): one exp/pair.
//
// Block: 1024 thr = 16 waves, 64 m per block (1 m/lane), n split 16 ways
// (64 n per wave, one ds_read_b128 per n). Grid: 8 x 64 = 512 blocks =
// 2 blocks/CU; __launch_bounds__(1024,8) caps VGPR<=64 -> 8 waves/SIMD.

#define OUTC 64
#define MB   64
#define NW   16   // waves per block

__global__ __launch_bounds__(1024, 8) void convdeepset_kernel(
    const float* __restrict__ x,     // [B,1024,2]
    const float* __restrict__ y,     // [B,1024]
    const float* __restrict__ t,     // [B,4096,2]
    const float* __restrict__ sigma, // [2]
    const float* __restrict__ W,     // [64,2]
    const float* __restrict__ bias,  // [64]
    float* __restrict__ out)         // [B,4096,64]
{
    __shared__ float4 pk[1024];          // 16 KB: (2sx, 2sy, q, y)
    __shared__ float  dens_part[NW*MB];  // 4 KB
    __shared__ float  conv_part[NW*MB];  // 4 KB
    __shared__ float  sums[2*MB];
    __shared__ float  dens_tot[MB];
    __shared__ float  ratio[MB];

    const int tid = threadIdx.x;
    const int b   = blockIdx.x >> 6;         // 64 m-tiles per batch
    const int m0  = (blockIdx.x & 63) * MB;

    const float log2e = 1.44269504088896340736f;
    const float k0 = -0.5f * __expf(-2.0f * sigma[0]) * log2e;
    const float k1 = -0.5f * __expf(-2.0f * sigma[1]) * log2e;
    const float s0 = sqrtf(-k0);
    const float r  = k1 / k0;                // conv exponent = r * arg

    // Stage: each thread builds one pk record (coalesced float2 + float).
    {
        const float2 xv = ((const float2*)(x + (size_t)b * 2048))[tid];
        const float  yv = y[(size_t)b * 1024 + tid];
        const float sx = xv.x * s0, sy = xv.y * s0;
        pk[tid] = make_float4(sx + sx, sy + sy,
                              -fmaf(sx, sx, sy * sy), yv);
    }

    const int wave = tid >> 6;
    const int lane = tid & 63;
    const float2 tv = ((const float2*)(t + ((size_t)b * 4096 + m0) * 2))[lane];
    const float u  = tv.x * s0;
    const float v  = tv.y * s0;
    const float cm = -fmaf(u, u, v * v);

    __syncthreads();

    float dacc = 0.f, cacc = 0.f;
    const int ibeg = wave * 64;              // 64 n per wave

    if (r == 1.0f) {
        #pragma unroll 4
        for (int i = ibeg; i < ibeg + 64; ++i) {
            const float4 p = pk[i];          // wave-broadcast b128
            float arg = fmaf(p.x, u, fmaf(p.y, v, p.z + cm));
            float e   = __builtin_amdgcn_exp2f(arg);
            dacc += e;
            cacc = fmaf(p.w, e, cacc);
        }
    } else {
        #pragma unroll 2
        for (int i = ibeg; i < ibeg + 64; ++i) {
            const float4 p = pk[i];
            float arg = fmaf(p.x, u, fmaf(p.y, v, p.z + cm));
            dacc += __builtin_amdgcn_exp2f(arg);
            cacc = fmaf(p.w, __builtin_amdgcn_exp2f(arg * r), cacc);
        }
    }

    dens_part[wave * MB + lane] = dacc;
    conv_part[wave * MB + lane] = cacc;
    __syncthreads();

    // Cross-wave reduce: 128 threads, one (channel, m) each, 16 partials.
    if (tid < 2 * MB) {
        const int m = tid & (MB - 1);
        const float* src = (tid < MB) ? dens_part : conv_part;
        float s = 0.f;
        #pragma unroll
        for (int w = 0; w < NW; ++w) s += src[w * MB + m];
        sums[tid] = s;
    }
    __syncthreads();
    if (tid < MB) {
        float dt = sums[tid];
        dens_tot[tid] = dt;
        ratio[tid]    = sums[MB + tid] / (dt + 1e-8f);
    }
    __syncthreads();

    // Epilogue: 64 m x 64 o; lane->o (coalesced), 16 groups x 4 m each.
    const int o = tid & 63;
    const int g = tid >> 6;
    const float w0 = W[o * 2 + 0];
    const float w1 = W[o * 2 + 1];
    const float bo = bias[o];
    float* outb = out + ((size_t)b * 4096 + m0) * OUTC;
    #pragma unroll
    for (int i = 0; i < 4; ++i) {
        int mm = g * 4 + i;
        outb[mm * OUTC + o] = fmaf(dens_tot[mm], w0, fmaf(ratio[mm], w1, bo));
    }
}

extern "C" void kernel_launch(void* const* d_in, const int* in_sizes, int n_in,
                              void* d_out, int out_size, void* d_ws, size_t ws_size,
                              hipStream_t stream) {
    const float* x     = (const float*)d_in[0];
    const float* y     = (const float*)d_in[1];
    const float* t     = (const float*)d_in[2];
    const float* sigma = (const float*)d_in[3];
    const float* W     = (const float*)d_in[4];
    const float* bias  = (const float*)d_in[5];
    float* out = (float*)d_out;

    // 8 batches x 64 m-tiles = 512 blocks (2/CU), 1024 threads each.
    convdeepset_kernel<<<dim3(512), dim3(1024), 0, stream>>>(
        x, y, t, sigma, W, bias, out);
}